// Round 10
// baseline (793.122 us; speedup 1.0000x reference)
//
#include <hip/hip_runtime.h>
#include <math.h>

#define NA 512
#define NN (NA*NA)
#define COULOMB 14.399645478425668f
#define SQRT_PI 1.7724538509055160273f

__device__ __forceinline__ float rl(float x, int lane) {
    return __int_as_float(__builtin_amdgcn_readlane(__float_as_int(x), lane));
}

__device__ __forceinline__ float pair_val(float dx, float dy, float dz,
                                          float s2i, float s2k) {
    float d2 = dx*dx + dy*dy + dz*dz;
    float rinv = rsqrtf(d2);
    return COULOMB * erff(d2 * rinv * rsqrtf(2.f * (s2i + s2k))) * rinv;
}

// ---------------------------------------------------------------- K1: per-atom
__global__ void k_pre(const float* __restrict__ feats, const float* __restrict__ w,
                      const int* __restrict__ type, const float* __restrict__ hard,
                      const float* __restrict__ sigma,
                      float* __restrict__ chi, float* __restrict__ diag,
                      float* __restrict__ sigA, int N) {
    __shared__ float wl[64];
    int tid = threadIdx.x;
    if (tid < 64) wl[tid] = w[tid];
    __syncthreads();
    int i = blockIdx.x * 256 + tid;
    if (i >= N) return;
    const float4* fp = (const float4*)(feats + (size_t)i * 64);
    float acc = 0.f;
#pragma unroll
    for (int q = 0; q < 16; q++) {
        float4 v = fp[q];
        acc += v.x * wl[4*q] + v.y * wl[4*q+1] + v.z * wl[4*q+2] + v.w * wl[4*q+3];
    }
    chi[i] = acc;
    int t = type[i];
    float s = sigma[t];
    float h = hard[t];
    sigA[i] = s;
    diag[i] = h * h + COULOMB / (SQRT_PI * s);
}

// ------------------------------------------- K2: diag factor + split panel trsm (all j)
__global__ void __launch_bounds__(256, 1) k_panel(const float* __restrict__ pos,
                                                  const float* __restrict__ sigA,
                                                  const float* __restrict__ diagA,
                                                  float* __restrict__ C, const int j) {
    const int q = blockIdx.x;
    const int b = blockIdx.y;
    float* __restrict__ Cb = C + (size_t)b * NN;
    const int jb = j * 64;
    const int m = NA - jb - 64;
    const int tid = threadIdx.x;
    __shared__ float D[64 * 65];
    __shared__ float DT[64 * 64];
    __shared__ float invd[64];
    __shared__ float px[NA], py[NA], pz[NA], s2s[NA];

    if (j == 0) {
#pragma unroll
        for (int e = 0; e < 2; e++) {
            int i = e * 256 + tid;
            px[i] = pos[((size_t)b * NA + i) * 3 + 0];
            py[i] = pos[((size_t)b * NA + i) * 3 + 1];
            pz[i] = pos[((size_t)b * NA + i) * 3 + 2];
            float s = sigA[b * NA + i];
            s2s[i] = s * s;
        }
        __syncthreads();
    }

#pragma unroll
    for (int e = 0; e < 16; e++) {
        int f = e * 256 + tid;
        int rr = f >> 6, cc = f & 63;
        float v;
        if (j == 0) {
            if (rr == cc) v = diagA[b * NA + rr];
            else v = pair_val(px[rr]-px[cc], py[rr]-py[cc], pz[rr]-pz[cc], s2s[rr], s2s[cc]);
        } else {
            v = Cb[(size_t)(jb + rr) * NA + jb + cc];
        }
        D[rr * 65 + cc] = v;
    }

    const int h = m >> 1;
    const int r0 = q ? h : 0;
    const int nr = q ? (m - h) : h;
    const int r = tid - 32;
    const bool hasrow = (r >= 0 && r < nr);
    const int grow = jb + 64 + r0 + r;
    float rv[64];
    if (hasrow) {
        if (j == 0) {
#pragma unroll
            for (int k = 0; k < 64; k++)
                rv[k] = pair_val(px[grow]-px[k], py[grow]-py[k], pz[grow]-pz[k],
                                 s2s[grow], s2s[k]);
        } else {
            const float4* rp = (const float4*)(Cb + (size_t)grow * NA + jb);
#pragma unroll
            for (int qq = 0; qq < 16; qq++) {
                float4 v = rp[qq];
                rv[4*qq] = v.x; rv[4*qq+1] = v.y; rv[4*qq+2] = v.z; rv[4*qq+3] = v.w;
            }
        }
    }
    __syncthreads();

    if (tid < 64) {
        const int t = tid;
        float cl[64];
#pragma unroll
        for (int i = 0; i < 64; i++) cl[i] = (i >= t) ? D[i * 65 + t] : D[t * 65 + i];
#pragma unroll
        for (int k = 0; k < 64; k++) {
            float pivot = rl(cl[k], k);
            float invp = 1.0f / pivot;
            float factor = (t > k) ? (cl[k] * invp) : 0.0f;
#pragma unroll
            for (int i = k + 1; i < 64; i++) {
                float bc = rl(cl[i], k);
                cl[i] -= bc * factor;
            }
        }
        float rs = 1.0f / sqrtf(cl[t]);
        invd[t] = rs;
#pragma unroll
        for (int i = 0; i < 64; i++)
            if (i >= t) D[i * 65 + t] = cl[i] * rs;
    }
    __syncthreads();

#pragma unroll
    for (int e = 0; e < 16; e++) {
        int f = e * 256 + tid;
        int row = f >> 6, cc = f & 63;
        float v = D[row * 65 + cc];
        DT[row * 64 + cc] = (cc < row) ? v : 0.f;
        if (q == 0 && cc <= row) Cb[(size_t)(jb + row) * NA + jb + cc] = v;
    }
    __syncthreads();

    if (hasrow) {
#pragma unroll
        for (int k = 0; k < 64; k++) {
            float acc = rv[k];
            const float4* Lr = (const float4*)(DT + k * 64);
            const int k4 = k >> 2;
#pragma unroll
            for (int t4 = 0; t4 < k4; t4++) {
                float4 Lv = Lr[t4];
                acc -= Lv.x * rv[4*t4] + Lv.y * rv[4*t4+1] + Lv.z * rv[4*t4+2] + Lv.w * rv[4*t4+3];
            }
#pragma unroll
            for (int tt = k4 * 4; tt < k; tt++) acc -= DT[k * 64 + tt] * rv[tt];
            rv[k] = acc * invd[k];
        }
        float4* rp = (float4*)(Cb + (size_t)grow * NA + jb);
#pragma unroll
        for (int qq = 0; qq < 16; qq++)
            rp[qq] = make_float4(rv[4*qq], rv[4*qq+1], rv[4*qq+2], rv[4*qq+3]);
    }
}

// ------------------------------------------- K3: trailing update (all j)
// 128x128 supertile, 256 threads, 8x8 acc. LDS halved vs round 9: stage 32
// k-columns per pass (two passes), As/Bs = 128x33 -> 33.8 KB total -> 4 blocks/CU
// (was 2 at stride-65/64-wide). Stride 33: ai reads hit 4 distinct banks, bj 16
// distinct; 2-way broadcast halves free (m136).
template<bool GEN>
__global__ void __launch_bounds__(256, 4) k_trail(float* __restrict__ C,
                                                  const float* __restrict__ pos,
                                                  const float* __restrict__ sigA,
                                                  const float* __restrict__ diagA,
                                                  const int j) {
    const int b = blockIdx.y;
    float* __restrict__ Cb = C + (size_t)b * NN;
    const int jb = j * 64;
    const int m = NA - jb - 64;
    int t = blockIdx.x;
    int RI = 0;
    while (t >= RI + 1) { t -= RI + 1; RI++; }
    const int RJ = t;
    const int RB = RI * 128, CB = RJ * 128;
    const int vr = min(128, m - RB);
    const int vc = min(128, m - CB);
    const int tid = threadIdx.x;
    const int rg = tid >> 4, cg = tid & 15;

    __shared__ float As[128 * 33];
    __shared__ float Bs[128 * 33];

    float acc[8][8];

    if (GEN) {
        __shared__ float pAx[128], pAy[128], pAz[128], sA[128], dA[128];
        __shared__ float pBx[128], pBy[128], pBz[128], sB[128];
        if (tid < 128) {
            if (RB + tid < m) {
                int ga = b * NA + jb + 64 + RB + tid;
                pAx[tid] = pos[(size_t)ga * 3 + 0];
                pAy[tid] = pos[(size_t)ga * 3 + 1];
                pAz[tid] = pos[(size_t)ga * 3 + 2];
                float s = sigA[ga]; sA[tid] = s * s;
                dA[tid] = diagA[ga];
            }
        } else {
            int u = tid - 128;
            if (CB + u < m) {
                int gb = b * NA + jb + 64 + CB + u;
                pBx[u] = pos[(size_t)gb * 3 + 0];
                pBy[u] = pos[(size_t)gb * 3 + 1];
                pBz[u] = pos[(size_t)gb * 3 + 2];
                float s = sigA[gb]; sB[u] = s * s;
            }
        }
        __syncthreads();
#pragma unroll
        for (int rr = 0; rr < 8; rr++) {
            int row = rg * 8 + rr;
#pragma unroll
            for (int cc = 0; cc < 8; cc++) {
                int col = cg + 16 * cc;
                if (RB + row == CB + col)
                    acc[rr][cc] = dA[row];
                else
                    acc[rr][cc] = pair_val(pAx[row]-pBx[col], pAy[row]-pBy[col],
                                           pAz[row]-pBz[col], sA[row], sB[col]);
            }
        }
    } else {
        const int GRB = jb + 64 + RB, GCB = jb + 64 + CB;
#pragma unroll
        for (int rr = 0; rr < 8; rr++) {
            int row = rg * 8 + rr;
#pragma unroll
            for (int cc = 0; cc < 8; cc++) {
                int col = cg + 16 * cc;
                acc[rr][cc] = (row < vr && col < vc)
                    ? Cb[(size_t)(GRB + row) * NA + GCB + col] : 0.f;
            }
        }
    }

    const float* Pan = Cb + (size_t)(jb + 64) * NA + jb;
    for (int kh = 0; kh < 2; kh++) {
        __syncthreads();   // GEN pos-LDS / previous pass reads complete
#pragma unroll
        for (int e = 0; e < 4; e++) {
            int f = e * 256 + tid;         // 1024 slots: 128 rows x 8 f4
            int row = f >> 3, s = f & 7;
            float4 v = make_float4(0.f, 0.f, 0.f, 0.f);
            if (row < vr) v = *(const float4*)(Pan + (size_t)(RB + row) * NA + kh * 32 + s * 4);
            As[row * 33 + s * 4 + 0] = v.x;
            As[row * 33 + s * 4 + 1] = v.y;
            As[row * 33 + s * 4 + 2] = v.z;
            As[row * 33 + s * 4 + 3] = v.w;
            float4 u = make_float4(0.f, 0.f, 0.f, 0.f);
            if (row < vc) u = *(const float4*)(Pan + (size_t)(CB + row) * NA + kh * 32 + s * 4);
            Bs[row * 33 + s * 4 + 0] = u.x;
            Bs[row * 33 + s * 4 + 1] = u.y;
            Bs[row * 33 + s * 4 + 2] = u.z;
            Bs[row * 33 + s * 4 + 3] = u.w;
        }
        __syncthreads();

#pragma unroll 4
        for (int k = 0; k < 32; k++) {
            float ai[8], bj[8];
#pragma unroll
            for (int rr = 0; rr < 8; rr++) ai[rr] = As[(rg * 8 + rr) * 33 + k];
#pragma unroll
            for (int cc = 0; cc < 8; cc++) bj[cc] = Bs[(cg + 16 * cc) * 33 + k];
#pragma unroll
            for (int rr = 0; rr < 8; rr++)
#pragma unroll
                for (int cc = 0; cc < 8; cc++)
                    acc[rr][cc] = fmaf(-ai[rr], bj[cc], acc[rr][cc]);
        }
    }

    const int GRB = jb + 64 + RB, GCB = jb + 64 + CB;
#pragma unroll
    for (int rr = 0; rr < 8; rr++) {
        int row = rg * 8 + rr;
        if (row < vr) {
#pragma unroll
            for (int cc = 0; cc < 8; cc++) {
                int col = cg + 16 * cc;
                if (col < vc)
                    Cb[(size_t)(GRB + row) * NA + GCB + col] = acc[rr][cc];
            }
        }
    }
}

// ------------------------------------------- K5: solve + outputs (round-4 proven)
__global__ void __launch_bounds__(512, 1) k_solve(const float* __restrict__ C,
                                                  const float* __restrict__ chiA,
                                                  const float* __restrict__ Qtot,
                                                  float* __restrict__ out, int B) {
    int b = blockIdx.x;
    const float* Cb = C + (size_t)b * NN;
    int tid = threadIdx.x;
    __shared__ float D[64 * 65];
    __shared__ float r1[NA], r2[NA];
    __shared__ float pb1[4][NA], pb2[4][NA];
    __shared__ float red[16];
    __shared__ float muS;

    r1[tid] = chiA[b * NA + tid];
    r2[tid] = 1.0f;

    const int sub = tid & 7;
    const int rowg = tid >> 3;

    for (int j = 0; j < 8; j++) {
        const int jb = j * 64;
        __syncthreads();
#pragma unroll
        for (int e = 0; e < 8; e++) {
            int f = e * 512 + tid;
            int row = f >> 6, cc = f & 63;
            D[row * 65 + cc] = Cb[(size_t)(jb + row) * NA + jb + cc];
        }
        __syncthreads();
        if (tid < 128) {
            int lane = tid & 63;
            float* vv = (tid < 64) ? r1 : r2;
            float val = vv[jb + lane];
            float idg = 1.0f / D[lane * 65 + lane];
#pragma unroll
            for (int k = 0; k < 64; k++) {
                float yk = rl(val, k) * rl(idg, k);
                if (lane == k) vv[jb + k] = yk;
                float lv = (lane > k) ? D[lane * 65 + k] : 0.f;
                val -= lv * yk;
            }
        }
        __syncthreads();
#pragma unroll
        for (int p = 0; p < 7; p++) {
            int g = jb + 64 + p * 64 + rowg;
            if (g < NA) {
                const float4* Lr = (const float4*)(Cb + (size_t)g * NA + jb + sub * 8);
                float4 a0 = Lr[0], a1 = Lr[1];
                int y0 = jb + sub * 8;
                float d1 = a0.x*r1[y0]   + a0.y*r1[y0+1] + a0.z*r1[y0+2] + a0.w*r1[y0+3]
                         + a1.x*r1[y0+4] + a1.y*r1[y0+5] + a1.z*r1[y0+6] + a1.w*r1[y0+7];
                float d2 = a0.x*r2[y0]   + a0.y*r2[y0+1] + a0.z*r2[y0+2] + a0.w*r2[y0+3]
                         + a1.x*r2[y0+4] + a1.y*r2[y0+5] + a1.z*r2[y0+6] + a1.w*r2[y0+7];
                d1 += __shfl_xor(d1, 1); d2 += __shfl_xor(d2, 1);
                d1 += __shfl_xor(d1, 2); d2 += __shfl_xor(d2, 2);
                d1 += __shfl_xor(d1, 4); d2 += __shfl_xor(d2, 4);
                if (sub == 0) { r1[g] -= d1; r2[g] -= d2; }
            }
        }
    }

    const int ii = tid & 127;
    const int gg = tid >> 7;
    for (int j = 7; j >= 0; j--) {
        const int jb = j * 64;
        __syncthreads();
#pragma unroll
        for (int e = 0; e < 8; e++) {
            int f = e * 512 + tid;
            int row = f >> 6, cc = f & 63;
            D[row * 65 + cc] = Cb[(size_t)(jb + row) * NA + jb + cc];
        }
        __syncthreads();
        if (tid < 128) {
            int lane = tid & 63;
            float* vv = (tid < 64) ? r1 : r2;
            float val = vv[jb + lane];
            float idg = 1.0f / D[lane * 65 + lane];
#pragma unroll
            for (int k = 63; k >= 0; k--) {
                float xk = rl(val, k) * rl(idg, k);
                if (lane == k) vv[jb + k] = xk;
                float lv = (lane < k) ? D[k * 65 + lane] : 0.f;
                val -= lv * xk;
            }
        }
        __syncthreads();
        if (jb > 0) {
            const int nf4 = jb >> 2;
            float4 s1 = make_float4(0.f,0.f,0.f,0.f), s2 = make_float4(0.f,0.f,0.f,0.f);
            if (ii < nf4) {
#pragma unroll
                for (int gq = 0; gq < 16; gq++) {
                    int g = jb + gg * 16 + gq;
                    float x1 = r1[g], x2 = r2[g];
                    float4 Lv = *(const float4*)(Cb + (size_t)g * NA + ii * 4);
                    s1.x += Lv.x * x1; s1.y += Lv.y * x1; s1.z += Lv.z * x1; s1.w += Lv.w * x1;
                    s2.x += Lv.x * x2; s2.y += Lv.y * x2; s2.z += Lv.z * x2; s2.w += Lv.w * x2;
                }
            }
            *(float4*)(&pb1[gg][ii * 4]) = s1;
            *(float4*)(&pb2[gg][ii * 4]) = s2;
            __syncthreads();
            if (tid < jb) {
                r1[tid] -= pb1[0][tid] + pb1[1][tid] + pb1[2][tid] + pb1[3][tid];
                r2[tid] -= pb2[0][tid] + pb2[1][tid] + pb2[2][tid] + pb2[3][tid];
            }
        }
    }
    __syncthreads();

    float s1p = r1[tid], s2p = r2[tid];
#pragma unroll
    for (int off = 1; off < 64; off <<= 1) {
        s1p += __shfl_xor(s1p, off);
        s2p += __shfl_xor(s2p, off);
    }
    if ((tid & 63) == 0) { red[tid >> 6] = s1p; red[8 + (tid >> 6)] = s2p; }
    __syncthreads();
    if (tid == 0) {
        float s1 = 0.f, s2 = 0.f;
#pragma unroll
        for (int wv = 0; wv < 8; wv++) { s1 += red[wv]; s2 += red[8 + wv]; }
        muS = -(Qtot[b] + s1) / s2;
    }
    __syncthreads();
    float mu = muS;
    float qv = -r1[tid] - mu * r2[tid];
    out[B + (size_t)b * NA + tid] = qv;

    float eacc = chiA[b * NA + tid] * qv;
#pragma unroll
    for (int off = 1; off < 64; off <<= 1) eacc += __shfl_xor(eacc, off);
    __syncthreads();
    if ((tid & 63) == 0) red[tid >> 6] = eacc;
    __syncthreads();
    if (tid == 0) {
        float e = 0.f;
#pragma unroll
        for (int wv = 0; wv < 8; wv++) e += red[wv];
        out[b] = 0.5f * e - 0.5f * mu * Qtot[b];
    }
}

// ---------------------------------------------------------------- host launch
extern "C" void kernel_launch(void* const* d_in, const int* in_sizes, int n_in,
                              void* d_out, int out_size, void* d_ws, size_t ws_size,
                              hipStream_t stream) {
    const int B = in_sizes[3];          // 128 molecules
    const int N = in_sizes[2];          // 65536 atoms
    const float* feats = (const float*)d_in[0];
    const float* pos   = (const float*)d_in[1];
    const int*   type  = (const int*)d_in[2];
    const float* Qt    = (const float*)d_in[3];
    const float* w     = (const float*)d_in[4];
    const float* hard  = (const float*)d_in[5];
    const float* sig   = (const float*)d_in[6];
    float* out = (float*)d_out;
    float* ws  = (float*)d_ws;

    float* C    = ws;                       // B * 512 * 512
    float* chi  = ws + (size_t)B * NN;      // N
    float* diag = chi + N;                  // N
    float* sigA = diag + N;                 // N

    k_pre<<<(N + 255) / 256, 256, 0, stream>>>(feats, w, type, hard, sig, chi, diag, sigA, N);

    static const int tilesJ[7] = {10, 6, 6, 3, 3, 1, 1};
    for (int j = 0; j < 8; j++) {
        k_panel<<<dim3(2, B), 256, 0, stream>>>(pos, sigA, diag, C, j);
        if (j < 7) {
            if (j == 0)
                k_trail<true><<<dim3(tilesJ[j], B), 256, 0, stream>>>(C, pos, sigA, diag, j);
            else
                k_trail<false><<<dim3(tilesJ[j], B), 256, 0, stream>>>(C, pos, sigA, diag, j);
        }
    }
    k_solve<<<B, 512, 0, stream>>>(C, chi, Qt, out, B);
}

// Round 11
// 750.409 us; speedup vs baseline: 1.0569x; 1.0569x over previous
//
#include <hip/hip_runtime.h>
#include <math.h>

#define NA 512
#define NN (NA*NA)
#define COULOMB 14.399645478425668f
#define SQRT_PI 1.7724538509055160273f

__device__ __forceinline__ float rl(float x, int lane) {
    return __int_as_float(__builtin_amdgcn_readlane(__float_as_int(x), lane));
}

__device__ __forceinline__ float pair_val(float dx, float dy, float dz,
                                          float s2i, float s2k) {
    float d2 = dx*dx + dy*dy + dz*dz;
    float rinv = rsqrtf(d2);
    return COULOMB * erff(d2 * rinv * rsqrtf(2.f * (s2i + s2k))) * rinv;
}

// ---------------------------------------------------------------- K1: per-atom
__global__ void k_pre(const float* __restrict__ feats, const float* __restrict__ w,
                      const int* __restrict__ type, const float* __restrict__ hard,
                      const float* __restrict__ sigma,
                      float* __restrict__ chi, float* __restrict__ diag,
                      float* __restrict__ sigA, int N) {
    __shared__ float wl[64];
    int tid = threadIdx.x;
    if (tid < 64) wl[tid] = w[tid];
    __syncthreads();
    int i = blockIdx.x * 256 + tid;
    if (i >= N) return;
    const float4* fp = (const float4*)(feats + (size_t)i * 64);
    float acc = 0.f;
#pragma unroll
    for (int q = 0; q < 16; q++) {
        float4 v = fp[q];
        acc += v.x * wl[4*q] + v.y * wl[4*q+1] + v.z * wl[4*q+2] + v.w * wl[4*q+3];
    }
    chi[i] = acc;
    int t = type[i];
    float s = sigma[t];
    float h = hard[t];
    sigA[i] = s;
    diag[i] = h * h + COULOMB / (SQRT_PI * s);
}

// ------------------------------------------- K2: diag factor + split panel trsm (all j)
__global__ void __launch_bounds__(256, 1) k_panel(const float* __restrict__ pos,
                                                  const float* __restrict__ sigA,
                                                  const float* __restrict__ diagA,
                                                  float* __restrict__ C, const int j) {
    const int q = blockIdx.x;
    const int b = blockIdx.y;
    float* __restrict__ Cb = C + (size_t)b * NN;
    const int jb = j * 64;
    const int m = NA - jb - 64;
    const int tid = threadIdx.x;
    __shared__ float D[64 * 65];
    __shared__ float DT[64 * 64];
    __shared__ float invd[64];
    __shared__ float px[NA], py[NA], pz[NA], s2s[NA];

    if (j == 0) {
#pragma unroll
        for (int e = 0; e < 2; e++) {
            int i = e * 256 + tid;
            px[i] = pos[((size_t)b * NA + i) * 3 + 0];
            py[i] = pos[((size_t)b * NA + i) * 3 + 1];
            pz[i] = pos[((size_t)b * NA + i) * 3 + 2];
            float s = sigA[b * NA + i];
            s2s[i] = s * s;
        }
        __syncthreads();
    }

#pragma unroll
    for (int e = 0; e < 16; e++) {
        int f = e * 256 + tid;
        int rr = f >> 6, cc = f & 63;
        float v;
        if (j == 0) {
            if (rr == cc) v = diagA[b * NA + rr];
            else v = pair_val(px[rr]-px[cc], py[rr]-py[cc], pz[rr]-pz[cc], s2s[rr], s2s[cc]);
        } else {
            v = Cb[(size_t)(jb + rr) * NA + jb + cc];
        }
        D[rr * 65 + cc] = v;
    }

    const int h = m >> 1;
    const int r0 = q ? h : 0;
    const int nr = q ? (m - h) : h;
    const int r = tid - 32;
    const bool hasrow = (r >= 0 && r < nr);
    const int grow = jb + 64 + r0 + r;
    float rv[64];
    if (hasrow) {
        if (j == 0) {
#pragma unroll
            for (int k = 0; k < 64; k++)
                rv[k] = pair_val(px[grow]-px[k], py[grow]-py[k], pz[grow]-pz[k],
                                 s2s[grow], s2s[k]);
        } else {
            const float4* rp = (const float4*)(Cb + (size_t)grow * NA + jb);
#pragma unroll
            for (int qq = 0; qq < 16; qq++) {
                float4 v = rp[qq];
                rv[4*qq] = v.x; rv[4*qq+1] = v.y; rv[4*qq+2] = v.z; rv[4*qq+3] = v.w;
            }
        }
    }
    __syncthreads();

    if (tid < 64) {
        const int t = tid;
        float cl[64];
#pragma unroll
        for (int i = 0; i < 64; i++) cl[i] = (i >= t) ? D[i * 65 + t] : D[t * 65 + i];
#pragma unroll
        for (int k = 0; k < 64; k++) {
            float pivot = rl(cl[k], k);
            float invp = 1.0f / pivot;
            float factor = (t > k) ? (cl[k] * invp) : 0.0f;
#pragma unroll
            for (int i = k + 1; i < 64; i++) {
                float bc = rl(cl[i], k);
                cl[i] -= bc * factor;
            }
        }
        float rs = 1.0f / sqrtf(cl[t]);
        invd[t] = rs;
#pragma unroll
        for (int i = 0; i < 64; i++)
            if (i >= t) D[i * 65 + t] = cl[i] * rs;
    }
    __syncthreads();

#pragma unroll
    for (int e = 0; e < 16; e++) {
        int f = e * 256 + tid;
        int row = f >> 6, cc = f & 63;
        float v = D[row * 65 + cc];
        DT[row * 64 + cc] = (cc < row) ? v : 0.f;
        if (q == 0 && cc <= row) Cb[(size_t)(jb + row) * NA + jb + cc] = v;
    }
    __syncthreads();

    if (hasrow) {
#pragma unroll
        for (int k = 0; k < 64; k++) {
            float acc = rv[k];
            const float4* Lr = (const float4*)(DT + k * 64);
            const int k4 = k >> 2;
#pragma unroll
            for (int t4 = 0; t4 < k4; t4++) {
                float4 Lv = Lr[t4];
                acc -= Lv.x * rv[4*t4] + Lv.y * rv[4*t4+1] + Lv.z * rv[4*t4+2] + Lv.w * rv[4*t4+3];
            }
#pragma unroll
            for (int tt = k4 * 4; tt < k; tt++) acc -= DT[k * 64 + tt] * rv[tt];
            rv[k] = acc * invd[k];
        }
        float4* rp = (float4*)(Cb + (size_t)grow * NA + jb);
#pragma unroll
        for (int qq = 0; qq < 16; qq++)
            rp[qq] = make_float4(rv[4*qq], rv[4*qq+1], rv[4*qq+2], rv[4*qq+3]);
    }
}

// ------------------------------------------- K3: trailing update (all j) — round-9 proven
template<bool GEN>
__global__ void __launch_bounds__(256, 3) k_trail(float* __restrict__ C,
                                                  const float* __restrict__ pos,
                                                  const float* __restrict__ sigA,
                                                  const float* __restrict__ diagA,
                                                  const int j) {
    const int b = blockIdx.y;
    float* __restrict__ Cb = C + (size_t)b * NN;
    const int jb = j * 64;
    const int m = NA - jb - 64;
    int t = blockIdx.x;
    int RI = 0;
    while (t >= RI + 1) { t -= RI + 1; RI++; }
    const int RJ = t;
    const int RB = RI * 128, CB = RJ * 128;
    const int vr = min(128, m - RB);
    const int vc = min(128, m - CB);
    const int tid = threadIdx.x;
    const int rg = tid >> 4, cg = tid & 15;

    __shared__ float As[128 * 65];
    __shared__ float Bs[128 * 65];

    float acc[8][8];

    if (GEN) {
        __shared__ float pAx[128], pAy[128], pAz[128], sA[128], dA[128];
        __shared__ float pBx[128], pBy[128], pBz[128], sB[128];
        if (tid < 128) {
            if (RB + tid < m) {
                int ga = b * NA + jb + 64 + RB + tid;
                pAx[tid] = pos[(size_t)ga * 3 + 0];
                pAy[tid] = pos[(size_t)ga * 3 + 1];
                pAz[tid] = pos[(size_t)ga * 3 + 2];
                float s = sigA[ga]; sA[tid] = s * s;
                dA[tid] = diagA[ga];
            }
        } else {
            int u = tid - 128;
            if (CB + u < m) {
                int gb = b * NA + jb + 64 + CB + u;
                pBx[u] = pos[(size_t)gb * 3 + 0];
                pBy[u] = pos[(size_t)gb * 3 + 1];
                pBz[u] = pos[(size_t)gb * 3 + 2];
                float s = sigA[gb]; sB[u] = s * s;
            }
        }
        __syncthreads();
#pragma unroll
        for (int rr = 0; rr < 8; rr++) {
            int row = rg * 8 + rr;
#pragma unroll
            for (int cc = 0; cc < 8; cc++) {
                int col = cg + 16 * cc;
                if (RB + row == CB + col)
                    acc[rr][cc] = dA[row];
                else
                    acc[rr][cc] = pair_val(pAx[row]-pBx[col], pAy[row]-pBy[col],
                                           pAz[row]-pBz[col], sA[row], sB[col]);
            }
        }
        __syncthreads();
    } else {
        const int GRB = jb + 64 + RB, GCB = jb + 64 + CB;
#pragma unroll
        for (int rr = 0; rr < 8; rr++) {
            int row = rg * 8 + rr;
#pragma unroll
            for (int cc = 0; cc < 8; cc++) {
                int col = cg + 16 * cc;
                acc[rr][cc] = (row < vr && col < vc)
                    ? Cb[(size_t)(GRB + row) * NA + GCB + col] : 0.f;
            }
        }
    }

    const float* Pan = Cb + (size_t)(jb + 64) * NA + jb;
#pragma unroll
    for (int e = 0; e < 8; e++) {
        int f = e * 256 + tid;
        int row = f >> 4, s = f & 15;
        float4 v = make_float4(0.f, 0.f, 0.f, 0.f);
        if (row < vr) v = *(const float4*)(Pan + (size_t)(RB + row) * NA + s * 4);
        As[row * 65 + s * 4 + 0] = v.x;
        As[row * 65 + s * 4 + 1] = v.y;
        As[row * 65 + s * 4 + 2] = v.z;
        As[row * 65 + s * 4 + 3] = v.w;
        float4 u = make_float4(0.f, 0.f, 0.f, 0.f);
        if (row < vc) u = *(const float4*)(Pan + (size_t)(CB + row) * NA + s * 4);
        Bs[row * 65 + s * 4 + 0] = u.x;
        Bs[row * 65 + s * 4 + 1] = u.y;
        Bs[row * 65 + s * 4 + 2] = u.z;
        Bs[row * 65 + s * 4 + 3] = u.w;
    }
    __syncthreads();

#pragma unroll 4
    for (int k = 0; k < 64; k++) {
        float ai[8], bj[8];
#pragma unroll
        for (int rr = 0; rr < 8; rr++) ai[rr] = As[(rg * 8 + rr) * 65 + k];
#pragma unroll
        for (int cc = 0; cc < 8; cc++) bj[cc] = Bs[(cg + 16 * cc) * 65 + k];
#pragma unroll
        for (int rr = 0; rr < 8; rr++)
#pragma unroll
            for (int cc = 0; cc < 8; cc++)
                acc[rr][cc] = fmaf(-ai[rr], bj[cc], acc[rr][cc]);
    }

    const int GRB = jb + 64 + RB, GCB = jb + 64 + CB;
#pragma unroll
    for (int rr = 0; rr < 8; rr++) {
        int row = rg * 8 + rr;
        if (row < vr) {
#pragma unroll
            for (int cc = 0; cc < 8; cc++) {
                int col = cg + 16 * cc;
                if (col < vc)
                    Cb[(size_t)(GRB + row) * NA + GCB + col] = acc[rr][cc];
            }
        }
    }
}

// ------------------------------------------- K4: single-RHS solve (grid = B x 2)
// rhs 0: x1 = C^-1 chi ; rhs 1: x2 = C^-1 1. 256 blocks -> all CUs active.
// Solution written to xout[b*NA + i].
__global__ void __launch_bounds__(512, 1) k_solve2(const float* __restrict__ C,
                                                   const float* __restrict__ chiA,
                                                   float* __restrict__ x1out,
                                                   float* __restrict__ x2out) {
    const int b = blockIdx.x;
    const int rhs = blockIdx.y;
    const float* Cb = C + (size_t)b * NN;
    const int tid = threadIdx.x;
    __shared__ float D[64 * 65];
    __shared__ float r[NA];
    __shared__ float pb[4][NA];

    r[tid] = rhs ? 1.0f : chiA[b * NA + tid];

    const int sub = tid & 7;
    const int rowg = tid >> 3;

    // -------- forward: L y = r
    for (int j = 0; j < 8; j++) {
        const int jb = j * 64;
        __syncthreads();
#pragma unroll
        for (int e = 0; e < 8; e++) {
            int f = e * 512 + tid;
            int row = f >> 6, cc = f & 63;
            D[row * 65 + cc] = Cb[(size_t)(jb + row) * NA + jb + cc];
        }
        __syncthreads();
        if (tid < 64) {
            float val = r[jb + tid];
            float idg = 1.0f / D[tid * 65 + tid];
#pragma unroll
            for (int k = 0; k < 64; k++) {
                float yk = rl(val, k) * rl(idg, k);
                if (tid == k) r[jb + k] = yk;
                float lv = (tid > k) ? D[tid * 65 + k] : 0.f;
                val -= lv * yk;
            }
        }
        __syncthreads();
#pragma unroll
        for (int p = 0; p < 7; p++) {
            int g = jb + 64 + p * 64 + rowg;
            if (g < NA) {
                const float4* Lr = (const float4*)(Cb + (size_t)g * NA + jb + sub * 8);
                float4 a0 = Lr[0], a1 = Lr[1];
                int y0 = jb + sub * 8;
                float d1 = a0.x*r[y0]   + a0.y*r[y0+1] + a0.z*r[y0+2] + a0.w*r[y0+3]
                         + a1.x*r[y0+4] + a1.y*r[y0+5] + a1.z*r[y0+6] + a1.w*r[y0+7];
                d1 += __shfl_xor(d1, 1);
                d1 += __shfl_xor(d1, 2);
                d1 += __shfl_xor(d1, 4);
                if (sub == 0) r[g] -= d1;
            }
        }
    }

    // -------- backward: L^T x = y
    const int ii = tid & 127;
    const int gg = tid >> 7;
    for (int j = 7; j >= 0; j--) {
        const int jb = j * 64;
        __syncthreads();
#pragma unroll
        for (int e = 0; e < 8; e++) {
            int f = e * 512 + tid;
            int row = f >> 6, cc = f & 63;
            D[row * 65 + cc] = Cb[(size_t)(jb + row) * NA + jb + cc];
        }
        __syncthreads();
        if (tid < 64) {
            float val = r[jb + tid];
            float idg = 1.0f / D[tid * 65 + tid];
#pragma unroll
            for (int k = 63; k >= 0; k--) {
                float xk = rl(val, k) * rl(idg, k);
                if (tid == k) r[jb + k] = xk;
                float lv = (tid < k) ? D[k * 65 + tid] : 0.f;
                val -= lv * xk;
            }
        }
        __syncthreads();
        if (jb > 0) {
            const int nf4 = jb >> 2;
            float4 s1 = make_float4(0.f, 0.f, 0.f, 0.f);
            if (ii < nf4) {
#pragma unroll
                for (int gq = 0; gq < 16; gq++) {
                    int g = jb + gg * 16 + gq;
                    float x1 = r[g];
                    float4 Lv = *(const float4*)(Cb + (size_t)g * NA + ii * 4);
                    s1.x += Lv.x * x1; s1.y += Lv.y * x1; s1.z += Lv.z * x1; s1.w += Lv.w * x1;
                }
            }
            *(float4*)(&pb[gg][ii * 4]) = s1;
            __syncthreads();
            if (tid < jb)
                r[tid] -= pb[0][tid] + pb[1][tid] + pb[2][tid] + pb[3][tid];
        }
    }
    __syncthreads();

    float* xo = rhs ? x2out : x1out;
    xo[(size_t)b * NA + tid] = r[tid];
}

// ------------------------------------------- K5: mu, q, energy from x1, x2
__global__ void __launch_bounds__(512, 1) k_final(const float* __restrict__ x1,
                                                  const float* __restrict__ x2,
                                                  const float* __restrict__ chiA,
                                                  const float* __restrict__ Qtot,
                                                  float* __restrict__ out, int B) {
    const int b = blockIdx.x;
    const int tid = threadIdx.x;
    __shared__ float red[16];
    __shared__ float muS;

    float v1 = x1[(size_t)b * NA + tid];
    float v2 = x2[(size_t)b * NA + tid];

    float s1p = v1, s2p = v2;
#pragma unroll
    for (int off = 1; off < 64; off <<= 1) {
        s1p += __shfl_xor(s1p, off);
        s2p += __shfl_xor(s2p, off);
    }
    if ((tid & 63) == 0) { red[tid >> 6] = s1p; red[8 + (tid >> 6)] = s2p; }
    __syncthreads();
    if (tid == 0) {
        float s1 = 0.f, s2 = 0.f;
#pragma unroll
        for (int wv = 0; wv < 8; wv++) { s1 += red[wv]; s2 += red[8 + wv]; }
        muS = -(Qtot[b] + s1) / s2;
    }
    __syncthreads();
    float mu = muS;
    float qv = -v1 - mu * v2;
    out[B + (size_t)b * NA + tid] = qv;

    float eacc = chiA[b * NA + tid] * qv;
#pragma unroll
    for (int off = 1; off < 64; off <<= 1) eacc += __shfl_xor(eacc, off);
    __syncthreads();
    if ((tid & 63) == 0) red[tid >> 6] = eacc;
    __syncthreads();
    if (tid == 0) {
        float e = 0.f;
#pragma unroll
        for (int wv = 0; wv < 8; wv++) e += red[wv];
        out[b] = 0.5f * e - 0.5f * mu * Qtot[b];
    }
}

// ---------------------------------------------------------------- host launch
extern "C" void kernel_launch(void* const* d_in, const int* in_sizes, int n_in,
                              void* d_out, int out_size, void* d_ws, size_t ws_size,
                              hipStream_t stream) {
    const int B = in_sizes[3];          // 128 molecules
    const int N = in_sizes[2];          // 65536 atoms
    const float* feats = (const float*)d_in[0];
    const float* pos   = (const float*)d_in[1];
    const int*   type  = (const int*)d_in[2];
    const float* Qt    = (const float*)d_in[3];
    const float* w     = (const float*)d_in[4];
    const float* hard  = (const float*)d_in[5];
    const float* sig   = (const float*)d_in[6];
    float* out = (float*)d_out;
    float* ws  = (float*)d_ws;

    float* C    = ws;                       // B * 512 * 512
    float* chi  = ws + (size_t)B * NN;      // N
    float* diag = chi + N;                  // N (reused as x1 after factorization)
    float* sigA = diag + N;                 // N (reused as x2 after factorization)

    k_pre<<<(N + 255) / 256, 256, 0, stream>>>(feats, w, type, hard, sig, chi, diag, sigA, N);

    static const int tilesJ[7] = {10, 6, 6, 3, 3, 1, 1};
    for (int j = 0; j < 8; j++) {
        k_panel<<<dim3(2, B), 256, 0, stream>>>(pos, sigA, diag, C, j);
        if (j < 7) {
            if (j == 0)
                k_trail<true><<<dim3(tilesJ[j], B), 256, 0, stream>>>(C, pos, sigA, diag, j);
            else
                k_trail<false><<<dim3(tilesJ[j], B), 256, 0, stream>>>(C, pos, sigA, diag, j);
        }
    }
    // diag/sigA are dead after the last panel/trail — reuse as x1/x2 storage.
    k_solve2<<<dim3(B, 2), 512, 0, stream>>>(C, chi, diag, sigA);
    k_final<<<B, 512, 0, stream>>>(diag, sigA, chi, Qt, out, B);
}